// Round 1
// baseline (4219.096 us; speedup 1.0000x reference)
//
#include <hip/hip_runtime.h>

#define NN 100000
#define NE 800000
#define DD 16
#define ALPHA 0.1f

__device__ __forceinline__ void load16(const float* __restrict__ p, float* r) {
  float4 v0 = *(const float4*)(p + 0);
  float4 v1 = *(const float4*)(p + 4);
  float4 v2 = *(const float4*)(p + 8);
  float4 v3 = *(const float4*)(p + 12);
  r[0]=v0.x; r[1]=v0.y; r[2]=v0.z; r[3]=v0.w;
  r[4]=v1.x; r[5]=v1.y; r[6]=v1.z; r[7]=v1.w;
  r[8]=v2.x; r[9]=v2.y; r[10]=v2.z; r[11]=v2.w;
  r[12]=v3.x; r[13]=v3.y; r[14]=v3.z; r[15]=v3.w;
}

__device__ __forceinline__ void store16(float* __restrict__ p, const float* r) {
  *(float4*)(p + 0)  = make_float4(r[0], r[1], r[2], r[3]);
  *(float4*)(p + 4)  = make_float4(r[4], r[5], r[6], r[7]);
  *(float4*)(p + 8)  = make_float4(r[8], r[9], r[10], r[11]);
  *(float4*)(p + 12) = make_float4(r[12], r[13], r[14], r[15]);
}

// ---------------------------------------------------------------------------
// Edge kernel: both message MLPs per edge, scatter-add to mess_to / mess_from
// tmp_to  = [h[dst], h[src], ea] -> phi_to  -> += mess_to[dst]
// tmp_from= [h[src], h[dst], ea] -> phi_from-> += mess_from[src]
// Self-loop edges (s==d) contribute nothing (sl_mask).
// ---------------------------------------------------------------------------
__global__ __launch_bounds__(256) void edge_kernel(
    const int* __restrict__ ei, const float* __restrict__ ea,
    const float* __restrict__ h,
    const float* __restrict__ to_w1, const float* __restrict__ to_b1,
    const float* __restrict__ to_w2, const float* __restrict__ to_b2,
    const float* __restrict__ fr_w1, const float* __restrict__ fr_b1,
    const float* __restrict__ fr_w2, const float* __restrict__ fr_b2,
    float* __restrict__ mto, float* __restrict__ mfr)
{
  // layout per half (848 floats): w1[560] b1[16] w2[256] b2[16]
  __shared__ float sw[1696];
  for (int i = threadIdx.x; i < 560; i += 256) { sw[i] = to_w1[i]; sw[848 + i] = fr_w1[i]; }
  { int i = threadIdx.x;
    if (i < 256) { sw[576 + i] = to_w2[i]; sw[848 + 576 + i] = fr_w2[i]; }
    if (i < 16) {
      sw[560 + i] = to_b1[i];
      sw[832 + i] = to_b2[i];
      sw[848 + 560 + i] = fr_b1[i];
      sw[848 + 832 + i] = fr_b2[i];
    }
  }
  __syncthreads();

  int e = blockIdx.x * 256 + threadIdx.x;
  if (e >= NE) return;
  int s = ei[e];
  int d = ei[NE + e];
  if (s == d) return;  // sl_mask == 0

  float hs[DD], hd[DD];
  load16(h + (size_t)s * DD, hs);
  load16(h + (size_t)d * DD, hd);
  float a0 = ea[3 * (size_t)e], a1 = ea[3 * (size_t)e + 1], a2 = ea[3 * (size_t)e + 2];

  #pragma unroll 1
  for (int pass = 0; pass < 2; ++pass) {
    const float* w1 = sw + (pass ? 848 : 0);
    const float* b1 = w1 + 560;
    const float* w2 = w1 + 576;
    const float* b2 = w1 + 832;
    float hid[DD];
    #pragma unroll
    for (int j = 0; j < DD; ++j) hid[j] = b1[j];
    #pragma unroll
    for (int i = 0; i < DD; ++i) {
      float x = pass ? hs[i] : hd[i];   // first 16 inputs
      #pragma unroll
      for (int j = 0; j < DD; ++j) hid[j] = fmaf(x, w1[i * DD + j], hid[j]);
    }
    #pragma unroll
    for (int i = 0; i < DD; ++i) {
      float x = pass ? hd[i] : hs[i];   // second 16 inputs
      #pragma unroll
      for (int j = 0; j < DD; ++j) hid[j] = fmaf(x, w1[(DD + i) * DD + j], hid[j]);
    }
    #pragma unroll
    for (int j = 0; j < DD; ++j) hid[j] = fmaf(a0, w1[32 * DD + j], hid[j]);
    #pragma unroll
    for (int j = 0; j < DD; ++j) hid[j] = fmaf(a1, w1[33 * DD + j], hid[j]);
    #pragma unroll
    for (int j = 0; j < DD; ++j) hid[j] = fmaf(a2, w1[34 * DD + j], hid[j]);
    #pragma unroll
    for (int j = 0; j < DD; ++j) hid[j] = fmaxf(hid[j], 0.0f);

    float out[DD];
    #pragma unroll
    for (int j = 0; j < DD; ++j) out[j] = b2[j];
    #pragma unroll
    for (int i = 0; i < DD; ++i) {
      float x = hid[i];
      #pragma unroll
      for (int j = 0; j < DD; ++j) out[j] = fmaf(x, w2[i * DD + j], out[j]);
    }

    float* dst = pass ? (mfr + (size_t)s * DD) : (mto + (size_t)d * DD);
    #pragma unroll
    for (int j = 0; j < DD; ++j) atomicAdd(dst + j, out[j]);
  }
}

// ---------------------------------------------------------------------------
// Node kernel: h += ALPHA * psi([h, mto, mfr, prb]); u = dec(h)
// ---------------------------------------------------------------------------
__global__ __launch_bounds__(256) void node_kernel(
    float* __restrict__ h, const float* __restrict__ mto, const float* __restrict__ mfr,
    const float* __restrict__ prb,
    const float* __restrict__ psi_w1, const float* __restrict__ psi_b1,
    const float* __restrict__ psi_w2, const float* __restrict__ psi_b2,
    const float* __restrict__ dec_w1, const float* __restrict__ dec_b1,
    const float* __restrict__ dec_w2, const float* __restrict__ dec_b2,
    float* __restrict__ u)
{
  // offsets: psi_w1 0 (784), psi_b1 784, psi_w2 800 (256), psi_b2 1056,
  //          dec_w1 1072 (256), dec_b1 1328, dec_w2 1344 (16), dec_b2 1360
  __shared__ float sw[1361];
  for (int i = threadIdx.x; i < 784; i += 256) sw[i] = psi_w1[i];
  { int i = threadIdx.x;
    if (i < 256) { sw[800 + i] = psi_w2[i]; sw[1072 + i] = dec_w1[i]; }
    if (i < 16) {
      sw[784 + i] = psi_b1[i];
      sw[1056 + i] = psi_b2[i];
      sw[1328 + i] = dec_b1[i];
      sw[1344 + i] = dec_w2[i];
    }
    if (i == 0) sw[1360] = dec_b2[0];
  }
  __syncthreads();

  int n = blockIdx.x * 256 + threadIdx.x;
  if (n >= NN) return;

  float hv[DD], mt[DD], mf[DD];
  load16(h + (size_t)n * DD, hv);
  load16(mto + (size_t)n * DD, mt);
  load16(mfr + (size_t)n * DD, mf);
  float p = prb[n];

  float hid[DD];
  #pragma unroll
  for (int j = 0; j < DD; ++j) hid[j] = sw[784 + j];
  #pragma unroll
  for (int i = 0; i < DD; ++i) {
    float x = hv[i];
    #pragma unroll
    for (int j = 0; j < DD; ++j) hid[j] = fmaf(x, sw[i * DD + j], hid[j]);
  }
  #pragma unroll
  for (int i = 0; i < DD; ++i) {
    float x = mt[i];
    #pragma unroll
    for (int j = 0; j < DD; ++j) hid[j] = fmaf(x, sw[(DD + i) * DD + j], hid[j]);
  }
  #pragma unroll
  for (int i = 0; i < DD; ++i) {
    float x = mf[i];
    #pragma unroll
    for (int j = 0; j < DD; ++j) hid[j] = fmaf(x, sw[(2 * DD + i) * DD + j], hid[j]);
  }
  #pragma unroll
  for (int j = 0; j < DD; ++j) hid[j] = fmaf(p, sw[48 * DD + j], hid[j]);
  #pragma unroll
  for (int j = 0; j < DD; ++j) hid[j] = fmaxf(hid[j], 0.0f);

  float hn[DD];
  #pragma unroll
  for (int j = 0; j < DD; ++j) hn[j] = sw[1056 + j];
  #pragma unroll
  for (int i = 0; i < DD; ++i) {
    float x = hid[i];
    #pragma unroll
    for (int j = 0; j < DD; ++j) hn[j] = fmaf(x, sw[800 + i * DD + j], hn[j]);
  }
  #pragma unroll
  for (int j = 0; j < DD; ++j) hn[j] = fmaf(ALPHA, hn[j], hv[j]);  // h + alpha*psi
  store16(h + (size_t)n * DD, hn);

  // dec MLP: 16 -> 16 relu -> 1
  float hid2[DD];
  #pragma unroll
  for (int j = 0; j < DD; ++j) hid2[j] = sw[1328 + j];
  #pragma unroll
  for (int i = 0; i < DD; ++i) {
    float x = hn[i];
    #pragma unroll
    for (int j = 0; j < DD; ++j) hid2[j] = fmaf(x, sw[1072 + i * DD + j], hid2[j]);
  }
  float uo = sw[1360];
  #pragma unroll
  for (int i = 0; i < DD; ++i) uo += fmaxf(hid2[i], 0.0f) * sw[1344 + i];
  u[n] = uo;
}

// ---------------------------------------------------------------------------
// Au[src] += a[e] * u[dst]   (all edges, incl. self-loops)
// ---------------------------------------------------------------------------
__global__ __launch_bounds__(256) void au_kernel(
    const int* __restrict__ ei, const float* __restrict__ a,
    const float* __restrict__ u, float* __restrict__ Au)
{
  int e = blockIdx.x * 256 + threadIdx.x;
  if (e >= NE) return;
  int s = ei[e];
  int d = ei[NE + e];
  atomicAdd(&Au[s], a[e] * u[d]);
}

// ---------------------------------------------------------------------------
// loss += w * sum((Au - y)^2)      (w = gamma^(K-1-t) / N)
// ---------------------------------------------------------------------------
__global__ __launch_bounds__(256) void loss_kernel(
    const float* __restrict__ Au, const float* __restrict__ y,
    float w, float* __restrict__ loss)
{
  float acc = 0.0f;
  for (int n = blockIdx.x * 256 + threadIdx.x; n < NN; n += gridDim.x * 256) {
    float dlt = Au[n] - y[n];
    acc += dlt * dlt;
  }
  #pragma unroll
  for (int off = 32; off > 0; off >>= 1) acc += __shfl_down(acc, off);
  __shared__ float ss[4];
  int lane = threadIdx.x & 63, wid = threadIdx.x >> 6;
  if (lane == 0) ss[wid] = acc;
  __syncthreads();
  if (threadIdx.x == 0) {
    float sum = ss[0] + ss[1] + ss[2] + ss[3];
    atomicAdd(loss, sum * w);
  }
}

extern "C" void kernel_launch(void* const* d_in, const int* in_sizes, int n_in,
                              void* d_out, int out_size, void* d_ws, size_t ws_size,
                              hipStream_t stream) {
  const int*   ei        = (const int*)d_in[0];
  const float* ea        = (const float*)d_in[1];
  const float* a_ij      = (const float*)d_in[2];
  const float* prb       = (const float*)d_in[3];
  // d_in[4] = sol (unused by reference)
  const float* y         = (const float*)d_in[5];
  const float* phi_to_w1 = (const float*)d_in[6];
  const float* phi_to_b1 = (const float*)d_in[7];
  const float* phi_to_w2 = (const float*)d_in[8];
  const float* phi_to_b2 = (const float*)d_in[9];
  const float* phi_fr_w1 = (const float*)d_in[10];
  const float* phi_fr_b1 = (const float*)d_in[11];
  const float* phi_fr_w2 = (const float*)d_in[12];
  const float* phi_fr_b2 = (const float*)d_in[13];
  const float* psi_w1    = (const float*)d_in[14];
  const float* psi_b1    = (const float*)d_in[15];
  const float* psi_w2    = (const float*)d_in[16];
  const float* psi_b2    = (const float*)d_in[17];
  const float* dec_w1    = (const float*)d_in[18];
  const float* dec_b1    = (const float*)d_in[19];
  const float* dec_w2    = (const float*)d_in[20];
  const float* dec_b2    = (const float*)d_in[21];

  float* out_u    = (float*)d_out;           // N floats
  float* out_loss = out_u + NN;              // 1 float

  float* h   = (float*)d_ws;                 // N*16
  float* mto = h + (size_t)NN * DD;          // N*16
  float* mfr = mto + (size_t)NN * DD;        // N*16
  float* Au  = mfr + (size_t)NN * DD;        // N

  hipMemsetAsync(h, 0, (size_t)NN * DD * sizeof(float), stream);
  hipMemsetAsync(out_loss, 0, sizeof(float), stream);

  const float gw[3] = {0.81f, 0.9f, 1.0f};   // gamma^(K-1-t)

  for (int t = 0; t < 3; ++t) {
    hipMemsetAsync(mto, 0, (size_t)NN * DD * sizeof(float), stream);
    hipMemsetAsync(mfr, 0, (size_t)NN * DD * sizeof(float), stream);

    edge_kernel<<<(NE + 255) / 256, 256, 0, stream>>>(
        ei, ea, h,
        phi_to_w1 + t * 560, phi_to_b1 + t * 16, phi_to_w2 + t * 256, phi_to_b2 + t * 16,
        phi_fr_w1 + t * 560, phi_fr_b1 + t * 16, phi_fr_w2 + t * 256, phi_fr_b2 + t * 16,
        mto, mfr);

    node_kernel<<<(NN + 255) / 256, 256, 0, stream>>>(
        h, mto, mfr, prb,
        psi_w1 + t * 784, psi_b1 + t * 16, psi_w2 + t * 256, psi_b2 + t * 16,
        dec_w1 + t * 256, dec_b1 + t * 16, dec_w2 + t * 16, dec_b2 + t,
        out_u);

    hipMemsetAsync(Au, 0, (size_t)NN * sizeof(float), stream);
    au_kernel<<<(NE + 255) / 256, 256, 0, stream>>>(ei, a_ij, out_u, Au);
    loss_kernel<<<200, 256, 0, stream>>>(Au, y, gw[t] / (float)NN, out_loss);
  }
}

// Round 2
// 609.876 us; speedup vs baseline: 6.9180x; 6.9180x over previous
//
#include <hip/hip_runtime.h>

#define NN 100000
#define NE 800000
#define DD 16
#define ALPHA 0.1f

__device__ __forceinline__ void load16(const float* __restrict__ p, float* r) {
  float4 v0 = *(const float4*)(p + 0);
  float4 v1 = *(const float4*)(p + 4);
  float4 v2 = *(const float4*)(p + 8);
  float4 v3 = *(const float4*)(p + 12);
  r[0]=v0.x; r[1]=v0.y; r[2]=v0.z; r[3]=v0.w;
  r[4]=v1.x; r[5]=v1.y; r[6]=v1.z; r[7]=v1.w;
  r[8]=v2.x; r[9]=v2.y; r[10]=v2.z; r[11]=v2.w;
  r[12]=v3.x; r[13]=v3.y; r[14]=v3.z; r[15]=v3.w;
}

__device__ __forceinline__ void store16(float* __restrict__ p, const float* r) {
  *(float4*)(p + 0)  = make_float4(r[0], r[1], r[2], r[3]);
  *(float4*)(p + 4)  = make_float4(r[4], r[5], r[6], r[7]);
  *(float4*)(p + 8)  = make_float4(r[8], r[9], r[10], r[11]);
  *(float4*)(p + 12) = make_float4(r[12], r[13], r[14], r[15]);
}

// ---------------------------------------------------------------------------
// CSR build: histogram -> 2-level exclusive scan -> payload scatter
// ---------------------------------------------------------------------------
__global__ __launch_bounds__(256) void hist_kernel(
    const int* __restrict__ ei, int* __restrict__ hist_dst, int* __restrict__ hist_src)
{
  int e = blockIdx.x * 256 + threadIdx.x;
  if (e >= NE) return;
  atomicAdd(&hist_src[ei[e]], 1);
  atomicAdd(&hist_dst[ei[NE + e]], 1);
}

// 1024 elems/block (256 thr x 4). Exclusive scan within block; block total -> sums[b].
__global__ __launch_bounds__(256) void scan1_kernel(
    const int* __restrict__ in, int* __restrict__ out, int* __restrict__ sums, int L)
{
  __shared__ int sh[256];
  int t = threadIdx.x;
  int i0 = blockIdx.x * 1024 + t * 4;
  int v0 = (i0 + 0 < L) ? in[i0 + 0] : 0;
  int v1 = (i0 + 1 < L) ? in[i0 + 1] : 0;
  int v2 = (i0 + 2 < L) ? in[i0 + 2] : 0;
  int v3 = (i0 + 3 < L) ? in[i0 + 3] : 0;
  int tot = v0 + v1 + v2 + v3;
  sh[t] = tot;
  __syncthreads();
  int val = tot;
  for (int off = 1; off < 256; off <<= 1) {
    int x = (t >= off) ? sh[t - off] : 0;
    __syncthreads();
    val += x; sh[t] = val;
    __syncthreads();
  }
  if (t == 255) sums[blockIdx.x] = val;
  int run = val - tot;  // exclusive prefix of this thread's chunk
  if (i0 + 0 < L) out[i0 + 0] = run; run += v0;
  if (i0 + 1 < L) out[i0 + 1] = run; run += v1;
  if (i0 + 2 < L) out[i0 + 2] = run; run += v2;
  if (i0 + 3 < L) out[i0 + 3] = run;
}

// single block: exclusive scan of block sums; writes grand total to *out_total
__global__ __launch_bounds__(256) void scan2_kernel(
    int* __restrict__ sums, int nb, int* __restrict__ out_total)
{
  __shared__ int sh[256];
  int t = threadIdx.x;
  int v = (t < nb) ? sums[t] : 0;
  sh[t] = v;
  __syncthreads();
  int val = v;
  for (int off = 1; off < 256; off <<= 1) {
    int x = (t >= off) ? sh[t - off] : 0;
    __syncthreads();
    val += x; sh[t] = val;
    __syncthreads();
  }
  if (t < nb) sums[t] = val - v;
  if (t == 255) *out_total = val;
}

__global__ __launch_bounds__(256) void scan3_kernel(
    int* __restrict__ out, const int* __restrict__ sums, int L)
{
  int i = blockIdx.x * 256 + threadIdx.x;
  if (i < L) out[i] += sums[i >> 10];
}

// payload scatter. pay_dst: dst-sorted {nbr=src(or -1 self-loop), ea0,ea1,ea2}
//                  pay_src: src-sorted {nbr=dst(or -1), ea0,ea1,ea2}
//                  pay_au : src-sorted {dst, a}   (self-loops INCLUDED)
__global__ __launch_bounds__(256) void scatter_kernel(
    const int* __restrict__ ei, const float* __restrict__ ea, const float* __restrict__ a,
    const int* __restrict__ base_dst, const int* __restrict__ base_src,
    int* __restrict__ cur_dst, int* __restrict__ cur_src,
    float4* __restrict__ pay_dst, float4* __restrict__ pay_src, float2* __restrict__ pay_au)
{
  int e = blockIdx.x * 256 + threadIdx.x;
  if (e >= NE) return;
  int s = ei[e];
  int d = ei[NE + e];
  float e0 = ea[3 * (size_t)e], e1 = ea[3 * (size_t)e + 1], e2 = ea[3 * (size_t)e + 2];
  int sl = (s == d);
  int pd = base_dst[d] + atomicAdd(&cur_dst[d], 1);
  pay_dst[pd] = make_float4(__int_as_float(sl ? -1 : s), e0, e1, e2);
  int ps = base_src[s] + atomicAdd(&cur_src[s], 1);
  pay_src[ps] = make_float4(__int_as_float(sl ? -1 : d), e0, e1, e2);
  pay_au[ps] = make_float2(__int_as_float(d), a[e]);
}

// ---------------------------------------------------------------------------
// Gather kernel: thread per (node, direction). Accumulates message sum in
// registers — zero atomics. h[own] half of layer 1 hoisted out of edge loop.
// ---------------------------------------------------------------------------
__global__ __launch_bounds__(256) void gather_kernel(
    const float* __restrict__ h,
    const float4* __restrict__ pay_dst, const float4* __restrict__ pay_src,
    const int* __restrict__ base_dst, const int* __restrict__ base_src,
    const float* __restrict__ to_w1, const float* __restrict__ to_b1,
    const float* __restrict__ to_w2, const float* __restrict__ to_b2,
    const float* __restrict__ fr_w1, const float* __restrict__ fr_b1,
    const float* __restrict__ fr_w2, const float* __restrict__ fr_b2,
    float* __restrict__ mto, float* __restrict__ mfr)
{
  // per half (848 floats): w1[560] b1[16] w2[256] b2[16]
  __shared__ float sw[1696];
  for (int i = threadIdx.x; i < 560; i += 256) { sw[i] = to_w1[i]; sw[848 + i] = fr_w1[i]; }
  { int i = threadIdx.x;
    if (i < 256) { sw[576 + i] = to_w2[i]; sw[848 + 576 + i] = fr_w2[i]; }
    if (i < 16) {
      sw[560 + i] = to_b1[i];
      sw[832 + i] = to_b2[i];
      sw[848 + 560 + i] = fr_b1[i];
      sw[848 + 832 + i] = fr_b2[i];
    }
  }
  __syncthreads();

  int tid = blockIdx.x * 256 + threadIdx.x;
  if (tid >= 2 * NN) return;
  int dir = (tid >= NN) ? 1 : 0;      // 0 = mess_to (by dst), 1 = mess_from (by src)
  int n = tid - (dir ? NN : 0);

  const float* w1 = sw + (dir ? 848 : 0);
  const float* b1 = w1 + 560;
  const float* w2 = w1 + 576;
  const float* b2 = w1 + 832;
  const float4* pay = dir ? pay_src : pay_dst;
  const int* base = dir ? base_src : base_dst;

  float hn[DD];
  load16(h + (size_t)n * DD, hn);

  // hoisted: first 16 input rows of W1 (own features) + bias
  float p1[DD];
  #pragma unroll
  for (int j = 0; j < DD; ++j) p1[j] = b1[j];
  #pragma unroll
  for (int i = 0; i < DD; ++i) {
    float x = hn[i];
    #pragma unroll
    for (int j = 0; j < DD; ++j) p1[j] = fmaf(x, w1[i * DD + j], p1[j]);
  }

  float ms[DD];
  #pragma unroll
  for (int j = 0; j < DD; ++j) ms[j] = 0.0f;

  int beg = base[n], end = base[n + 1];
  for (int i = beg; i < end; ++i) {
    float4 q = pay[i];
    int nb = __float_as_int(q.x);
    if (nb >= 0) {
      float hb[DD];
      load16(h + (size_t)nb * DD, hb);
      float hid[DD];
      #pragma unroll
      for (int j = 0; j < DD; ++j)
        hid[j] = fmaf(q.y, w1[32 * DD + j],
                 fmaf(q.z, w1[33 * DD + j],
                 fmaf(q.w, w1[34 * DD + j], p1[j])));
      #pragma unroll
      for (int k = 0; k < DD; ++k) {
        float x = hb[k];
        #pragma unroll
        for (int j = 0; j < DD; ++j) hid[j] = fmaf(x, w1[(DD + k) * DD + j], hid[j]);
      }
      #pragma unroll
      for (int j = 0; j < DD; ++j) hid[j] = fmaxf(hid[j], 0.0f);
      #pragma unroll
      for (int j = 0; j < DD; ++j) ms[j] += b2[j];
      #pragma unroll
      for (int k = 0; k < DD; ++k) {
        float x = hid[k];
        #pragma unroll
        for (int j = 0; j < DD; ++j) ms[j] = fmaf(x, w2[k * DD + j], ms[j]);
      }
    }
  }
  store16((dir ? mfr : mto) + (size_t)n * DD, ms);
}

// ---------------------------------------------------------------------------
// Node kernel: h += ALPHA * psi([h, mto, mfr, prb]); u = dec(h)
// ---------------------------------------------------------------------------
__global__ __launch_bounds__(256) void node_kernel(
    float* __restrict__ h, const float* __restrict__ mto, const float* __restrict__ mfr,
    const float* __restrict__ prb,
    const float* __restrict__ psi_w1, const float* __restrict__ psi_b1,
    const float* __restrict__ psi_w2, const float* __restrict__ psi_b2,
    const float* __restrict__ dec_w1, const float* __restrict__ dec_b1,
    const float* __restrict__ dec_w2, const float* __restrict__ dec_b2,
    float* __restrict__ u)
{
  __shared__ float sw[1361];
  for (int i = threadIdx.x; i < 784; i += 256) sw[i] = psi_w1[i];
  { int i = threadIdx.x;
    if (i < 256) { sw[800 + i] = psi_w2[i]; sw[1072 + i] = dec_w1[i]; }
    if (i < 16) {
      sw[784 + i] = psi_b1[i];
      sw[1056 + i] = psi_b2[i];
      sw[1328 + i] = dec_b1[i];
      sw[1344 + i] = dec_w2[i];
    }
    if (i == 0) sw[1360] = dec_b2[0];
  }
  __syncthreads();

  int n = blockIdx.x * 256 + threadIdx.x;
  if (n >= NN) return;

  float hv[DD], mt[DD], mf[DD];
  load16(h + (size_t)n * DD, hv);
  load16(mto + (size_t)n * DD, mt);
  load16(mfr + (size_t)n * DD, mf);
  float p = prb[n];

  float hid[DD];
  #pragma unroll
  for (int j = 0; j < DD; ++j) hid[j] = sw[784 + j];
  #pragma unroll
  for (int i = 0; i < DD; ++i) {
    float x = hv[i];
    #pragma unroll
    for (int j = 0; j < DD; ++j) hid[j] = fmaf(x, sw[i * DD + j], hid[j]);
  }
  #pragma unroll
  for (int i = 0; i < DD; ++i) {
    float x = mt[i];
    #pragma unroll
    for (int j = 0; j < DD; ++j) hid[j] = fmaf(x, sw[(DD + i) * DD + j], hid[j]);
  }
  #pragma unroll
  for (int i = 0; i < DD; ++i) {
    float x = mf[i];
    #pragma unroll
    for (int j = 0; j < DD; ++j) hid[j] = fmaf(x, sw[(2 * DD + i) * DD + j], hid[j]);
  }
  #pragma unroll
  for (int j = 0; j < DD; ++j) hid[j] = fmaf(p, sw[48 * DD + j], hid[j]);
  #pragma unroll
  for (int j = 0; j < DD; ++j) hid[j] = fmaxf(hid[j], 0.0f);

  float hnew[DD];
  #pragma unroll
  for (int j = 0; j < DD; ++j) hnew[j] = sw[1056 + j];
  #pragma unroll
  for (int i = 0; i < DD; ++i) {
    float x = hid[i];
    #pragma unroll
    for (int j = 0; j < DD; ++j) hnew[j] = fmaf(x, sw[800 + i * DD + j], hnew[j]);
  }
  #pragma unroll
  for (int j = 0; j < DD; ++j) hnew[j] = fmaf(ALPHA, hnew[j], hv[j]);
  store16(h + (size_t)n * DD, hnew);

  float hid2[DD];
  #pragma unroll
  for (int j = 0; j < DD; ++j) hid2[j] = sw[1328 + j];
  #pragma unroll
  for (int i = 0; i < DD; ++i) {
    float x = hnew[i];
    #pragma unroll
    for (int j = 0; j < DD; ++j) hid2[j] = fmaf(x, sw[1072 + i * DD + j], hid2[j]);
  }
  float uo = sw[1360];
  #pragma unroll
  for (int i = 0; i < DD; ++i) uo += fmaxf(hid2[i], 0.0f) * sw[1344 + i];
  u[n] = uo;
}

// ---------------------------------------------------------------------------
// Fused Au + loss: Au[n] = sum over out-edges a[e]*u[dst[e]] (self-loops in);
// loss += w * sum((Au-y)^2). One block-level atomic.
// ---------------------------------------------------------------------------
__global__ __launch_bounds__(256) void au_loss_kernel(
    const int* __restrict__ base_src, const float2* __restrict__ pay_au,
    const float* __restrict__ u, const float* __restrict__ y,
    float w, float* __restrict__ loss)
{
  int n = blockIdx.x * 256 + threadIdx.x;
  float acc = 0.0f;
  if (n < NN) {
    float au = 0.0f;
    int beg = base_src[n], end = base_src[n + 1];
    for (int i = beg; i < end; ++i) {
      float2 q = pay_au[i];
      au = fmaf(q.y, u[__float_as_int(q.x)], au);
    }
    float dlt = au - y[n];
    acc = dlt * dlt;
  }
  #pragma unroll
  for (int off = 32; off > 0; off >>= 1) acc += __shfl_down(acc, off);
  __shared__ float ss[4];
  int lane = threadIdx.x & 63, wid = threadIdx.x >> 6;
  if (lane == 0) ss[wid] = acc;
  __syncthreads();
  if (threadIdx.x == 0) {
    atomicAdd(loss, (ss[0] + ss[1] + ss[2] + ss[3]) * w);
  }
}

extern "C" void kernel_launch(void* const* d_in, const int* in_sizes, int n_in,
                              void* d_out, int out_size, void* d_ws, size_t ws_size,
                              hipStream_t stream) {
  const int*   ei        = (const int*)d_in[0];
  const float* ea        = (const float*)d_in[1];
  const float* a_ij      = (const float*)d_in[2];
  const float* prb       = (const float*)d_in[3];
  const float* y         = (const float*)d_in[5];
  const float* phi_to_w1 = (const float*)d_in[6];
  const float* phi_to_b1 = (const float*)d_in[7];
  const float* phi_to_w2 = (const float*)d_in[8];
  const float* phi_to_b2 = (const float*)d_in[9];
  const float* phi_fr_w1 = (const float*)d_in[10];
  const float* phi_fr_b1 = (const float*)d_in[11];
  const float* phi_fr_w2 = (const float*)d_in[12];
  const float* phi_fr_b2 = (const float*)d_in[13];
  const float* psi_w1    = (const float*)d_in[14];
  const float* psi_b1    = (const float*)d_in[15];
  const float* psi_w2    = (const float*)d_in[16];
  const float* psi_b2    = (const float*)d_in[17];
  const float* dec_w1    = (const float*)d_in[18];
  const float* dec_b1    = (const float*)d_in[19];
  const float* dec_w2    = (const float*)d_in[20];
  const float* dec_b2    = (const float*)d_in[21];

  float* out_u    = (float*)d_out;
  float* out_loss = out_u + NN;

  // workspace carve-up (16B aligned chunks)
  char* wp = (char*)d_ws;
  auto carve = [&](size_t bytes) { void* p = (void*)wp; wp += (bytes + 15) & ~(size_t)15; return p; };
  float4* pay_dst  = (float4*)carve((size_t)NE * 16);
  float4* pay_src  = (float4*)carve((size_t)NE * 16);
  float2* pay_au   = (float2*)carve((size_t)NE * 8);
  float*  h        = (float*)carve((size_t)NN * DD * 4);
  float*  mto      = (float*)carve((size_t)NN * DD * 4);
  float*  mfr      = (float*)carve((size_t)NN * DD * 4);
  int*    base_dst = (int*)carve((size_t)(NN + 1) * 4);
  int*    base_src = (int*)carve((size_t)(NN + 1) * 4);
  int*    hist_dst = (int*)carve((size_t)NN * 4);
  int*    hist_src = (int*)carve((size_t)NN * 4);   // contiguous after hist_dst
  int*    cur_dst  = (int*)carve((size_t)NN * 4);
  int*    cur_src  = (int*)carve((size_t)NN * 4);
  int*    sums     = (int*)carve(256 * 4);

  hipMemsetAsync(h, 0, (size_t)NN * DD * 4, stream);
  hipMemsetAsync(out_loss, 0, 4, stream);
  hipMemsetAsync(hist_dst, 0, (size_t)NN * 4, stream);
  hipMemsetAsync(hist_src, 0, (size_t)NN * 4, stream);
  hipMemsetAsync(cur_dst, 0, (size_t)NN * 4, stream);
  hipMemsetAsync(cur_src, 0, (size_t)NN * 4, stream);

  const int EB = (NE + 255) / 256;          // 3125
  const int NB = (NN + 255) / 256;          // 391
  const int SB1 = (NN + 1023) / 1024;       // 98

  hist_kernel<<<EB, 256, 0, stream>>>(ei, hist_dst, hist_src);

  scan1_kernel<<<SB1, 256, 0, stream>>>(hist_dst, base_dst, sums, NN);
  scan2_kernel<<<1, 256, 0, stream>>>(sums, SB1, base_dst + NN);
  scan3_kernel<<<NB, 256, 0, stream>>>(base_dst, sums, NN);

  scan1_kernel<<<SB1, 256, 0, stream>>>(hist_src, base_src, sums, NN);
  scan2_kernel<<<1, 256, 0, stream>>>(sums, SB1, base_src + NN);
  scan3_kernel<<<NB, 256, 0, stream>>>(base_src, sums, NN);

  scatter_kernel<<<EB, 256, 0, stream>>>(ei, ea, a_ij, base_dst, base_src,
                                         cur_dst, cur_src, pay_dst, pay_src, pay_au);

  const float gw[3] = {0.81f, 0.9f, 1.0f};  // gamma^(K-1-t)
  const int GB = (2 * NN + 255) / 256;      // 782

  for (int t = 0; t < 3; ++t) {
    gather_kernel<<<GB, 256, 0, stream>>>(
        h, pay_dst, pay_src, base_dst, base_src,
        phi_to_w1 + t * 560, phi_to_b1 + t * 16, phi_to_w2 + t * 256, phi_to_b2 + t * 16,
        phi_fr_w1 + t * 560, phi_fr_b1 + t * 16, phi_fr_w2 + t * 256, phi_fr_b2 + t * 16,
        mto, mfr);

    node_kernel<<<NB, 256, 0, stream>>>(
        h, mto, mfr, prb,
        psi_w1 + t * 784, psi_b1 + t * 16, psi_w2 + t * 256, psi_b2 + t * 16,
        dec_w1 + t * 256, dec_b1 + t * 16, dec_w2 + t * 16, dec_b2 + t,
        out_u);

    au_loss_kernel<<<NB, 256, 0, stream>>>(base_src, pay_au, out_u, y,
                                           gw[t] / (float)NN, out_loss);
  }
}

// Round 3
// 485.685 us; speedup vs baseline: 8.6869x; 1.2557x over previous
//
#include <hip/hip_runtime.h>

#define NN 100000
#define NE 800000
#define DD 16
#define ALPHA 0.1f

__device__ __forceinline__ void load16(const float* __restrict__ p, float* r) {
  float4 v0 = *(const float4*)(p + 0);
  float4 v1 = *(const float4*)(p + 4);
  float4 v2 = *(const float4*)(p + 8);
  float4 v3 = *(const float4*)(p + 12);
  r[0]=v0.x; r[1]=v0.y; r[2]=v0.z; r[3]=v0.w;
  r[4]=v1.x; r[5]=v1.y; r[6]=v1.z; r[7]=v1.w;
  r[8]=v2.x; r[9]=v2.y; r[10]=v2.z; r[11]=v2.w;
  r[12]=v3.x; r[13]=v3.y; r[14]=v3.z; r[15]=v3.w;
}

__device__ __forceinline__ void store16(float* __restrict__ p, const float* r) {
  *(float4*)(p + 0)  = make_float4(r[0], r[1], r[2], r[3]);
  *(float4*)(p + 4)  = make_float4(r[4], r[5], r[6], r[7]);
  *(float4*)(p + 8)  = make_float4(r[8], r[9], r[10], r[11]);
  *(float4*)(p + 12) = make_float4(r[12], r[13], r[14], r[15]);
}

// ---------------------------------------------------------------------------
// hist + rank: per-key histogram; the atomic's old value is this edge's
// stable-within-run rank inside its key's CSR segment.
// ---------------------------------------------------------------------------
__global__ __launch_bounds__(256) void hist_kernel(
    const int* __restrict__ ei,
    int* __restrict__ hist_dst, int* __restrict__ hist_src,
    int* __restrict__ rank_dst, int* __restrict__ rank_src)
{
  int e = blockIdx.x * 256 + threadIdx.x;
  if (e >= NE) return;
  int s = ei[e];
  int d = ei[NE + e];
  rank_src[e] = atomicAdd(&hist_src[s], 1);
  rank_dst[e] = atomicAdd(&hist_dst[d], 1);
}

// 1024 elems/block (256 thr x 4). Exclusive scan within block; block total -> sums[b].
__global__ __launch_bounds__(256) void scan1_kernel(
    const int* __restrict__ in, int* __restrict__ out, int* __restrict__ sums, int L)
{
  __shared__ int sh[256];
  int t = threadIdx.x;
  int i0 = blockIdx.x * 1024 + t * 4;
  int v0 = (i0 + 0 < L) ? in[i0 + 0] : 0;
  int v1 = (i0 + 1 < L) ? in[i0 + 1] : 0;
  int v2 = (i0 + 2 < L) ? in[i0 + 2] : 0;
  int v3 = (i0 + 3 < L) ? in[i0 + 3] : 0;
  int tot = v0 + v1 + v2 + v3;
  sh[t] = tot;
  __syncthreads();
  int val = tot;
  for (int off = 1; off < 256; off <<= 1) {
    int x = (t >= off) ? sh[t - off] : 0;
    __syncthreads();
    val += x; sh[t] = val;
    __syncthreads();
  }
  if (t == 255) sums[blockIdx.x] = val;
  int run = val - tot;
  if (i0 + 0 < L) out[i0 + 0] = run; run += v0;
  if (i0 + 1 < L) out[i0 + 1] = run; run += v1;
  if (i0 + 2 < L) out[i0 + 2] = run; run += v2;
  if (i0 + 3 < L) out[i0 + 3] = run;
}

__global__ __launch_bounds__(256) void scan2_kernel(
    int* __restrict__ sums, int nb, int* __restrict__ out_total)
{
  __shared__ int sh[256];
  int t = threadIdx.x;
  int v = (t < nb) ? sums[t] : 0;
  sh[t] = v;
  __syncthreads();
  int val = v;
  for (int off = 1; off < 256; off <<= 1) {
    int x = (t >= off) ? sh[t - off] : 0;
    __syncthreads();
    val += x; sh[t] = val;
    __syncthreads();
  }
  if (t < nb) sums[t] = val - v;
  if (t == 255) *out_total = val;
}

__global__ __launch_bounds__(256) void scan3_kernel(
    int* __restrict__ out, const int* __restrict__ sums, int L)
{
  int i = blockIdx.x * 256 + threadIdx.x;
  if (i < L) out[i] += sums[i >> 10];
}

// payload scatter — atomic-free (positions from base + precomputed rank).
__global__ __launch_bounds__(256) void scatter_kernel(
    const int* __restrict__ ei, const float* __restrict__ ea, const float* __restrict__ a,
    const int* __restrict__ base_dst, const int* __restrict__ base_src,
    const int* __restrict__ rank_dst, const int* __restrict__ rank_src,
    float4* __restrict__ pay_dst, float4* __restrict__ pay_src, float2* __restrict__ pay_au)
{
  int e = blockIdx.x * 256 + threadIdx.x;
  if (e >= NE) return;
  int s = ei[e];
  int d = ei[NE + e];
  float e0 = ea[3 * (size_t)e], e1 = ea[3 * (size_t)e + 1], e2 = ea[3 * (size_t)e + 2];
  int sl = (s == d);
  int pd = base_dst[d] + rank_dst[e];
  pay_dst[pd] = make_float4(__int_as_float(sl ? -1 : s), e0, e1, e2);
  int ps = base_src[s] + rank_src[e];
  pay_src[ps] = make_float4(__int_as_float(sl ? -1 : d), e0, e1, e2);
  pay_au[ps] = make_float2(__int_as_float(d), a[e]);
}

// ---------------------------------------------------------------------------
// Gather: thread per (node, direction). Per-edge work is LAYER 1 ONLY
// (W2 is edge-invariant: sum relu(hid) first, apply layer 2 once).
// ---------------------------------------------------------------------------
__global__ __launch_bounds__(256) void gather_kernel(
    const float* __restrict__ h,
    const float4* __restrict__ pay_dst, const float4* __restrict__ pay_src,
    const int* __restrict__ base_dst, const int* __restrict__ base_src,
    const float* __restrict__ to_w1, const float* __restrict__ to_b1,
    const float* __restrict__ to_w2, const float* __restrict__ to_b2,
    const float* __restrict__ fr_w1, const float* __restrict__ fr_b1,
    const float* __restrict__ fr_w2, const float* __restrict__ fr_b2,
    float* __restrict__ mto, float* __restrict__ mfr)
{
  // per half (848 floats): w1[560] b1[16] w2[256] b2[16]
  __shared__ float sw[1696];
  for (int i = threadIdx.x; i < 560; i += 256) { sw[i] = to_w1[i]; sw[848 + i] = fr_w1[i]; }
  { int i = threadIdx.x;
    if (i < 256) { sw[576 + i] = to_w2[i]; sw[848 + 576 + i] = fr_w2[i]; }
    if (i < 16) {
      sw[560 + i] = to_b1[i];
      sw[832 + i] = to_b2[i];
      sw[848 + 560 + i] = fr_b1[i];
      sw[848 + 832 + i] = fr_b2[i];
    }
  }
  __syncthreads();

  int tid = blockIdx.x * 256 + threadIdx.x;
  if (tid >= 2 * NN) return;
  int dir = (tid >= NN) ? 1 : 0;      // 0 = mess_to (by dst), 1 = mess_from (by src)
  int n = tid - (dir ? NN : 0);

  const float* w1 = sw + (dir ? 848 : 0);
  const float* b1 = w1 + 560;
  const float* w2 = w1 + 576;
  const float* b2 = w1 + 832;
  const float4* pay = dir ? pay_src : pay_dst;
  const int* base = dir ? base_src : base_dst;

  float hn[DD];
  load16(h + (size_t)n * DD, hn);

  // hoisted: own-feature half of layer 1 + bias
  float p1[DD];
  #pragma unroll
  for (int j = 0; j < DD; ++j) p1[j] = b1[j];
  #pragma unroll
  for (int i = 0; i < DD; ++i) {
    float x = hn[i];
    #pragma unroll
    for (int j = 0; j < DD; ++j) p1[j] = fmaf(x, w1[i * DD + j], p1[j]);
  }

  float hs_[DD];   // sum of relu(hidden) over valid edges
  #pragma unroll
  for (int j = 0; j < DD; ++j) hs_[j] = 0.0f;
  int cnt = 0;

  int beg = base[n], end = base[n + 1];
  if (beg < end) {
    float4 q = pay[beg];
    for (int i = beg; i < end; ++i) {
      float4 qn = (i + 1 < end) ? pay[i + 1] : q;   // prefetch next payload
      int nb = __float_as_int(q.x);
      if (nb >= 0) {
        float hb[DD];
        load16(h + (size_t)nb * DD, hb);
        float hid[DD];
        #pragma unroll
        for (int j = 0; j < DD; ++j)
          hid[j] = fmaf(q.y, w1[32 * DD + j],
                   fmaf(q.z, w1[33 * DD + j],
                   fmaf(q.w, w1[34 * DD + j], p1[j])));
        #pragma unroll
        for (int k = 0; k < DD; ++k) {
          float x = hb[k];
          #pragma unroll
          for (int j = 0; j < DD; ++j) hid[j] = fmaf(x, w1[(DD + k) * DD + j], hid[j]);
        }
        #pragma unroll
        for (int j = 0; j < DD; ++j) hs_[j] += fmaxf(hid[j], 0.0f);
        ++cnt;
      }
      q = qn;
    }
  }

  // layer 2 applied once to the summed hidden
  float ms[DD];
  float c = (float)cnt;
  #pragma unroll
  for (int j = 0; j < DD; ++j) ms[j] = c * b2[j];
  #pragma unroll
  for (int k = 0; k < DD; ++k) {
    float x = hs_[k];
    #pragma unroll
    for (int j = 0; j < DD; ++j) ms[j] = fmaf(x, w2[k * DD + j], ms[j]);
  }
  store16((dir ? mfr : mto) + (size_t)n * DD, ms);
}

// ---------------------------------------------------------------------------
// Node kernel: h += ALPHA * psi([h, mto, mfr, prb]); u = dec(h)
// ---------------------------------------------------------------------------
__global__ __launch_bounds__(256) void node_kernel(
    float* __restrict__ h, const float* __restrict__ mto, const float* __restrict__ mfr,
    const float* __restrict__ prb,
    const float* __restrict__ psi_w1, const float* __restrict__ psi_b1,
    const float* __restrict__ psi_w2, const float* __restrict__ psi_b2,
    const float* __restrict__ dec_w1, const float* __restrict__ dec_b1,
    const float* __restrict__ dec_w2, const float* __restrict__ dec_b2,
    float* __restrict__ u)
{
  __shared__ float sw[1361];
  for (int i = threadIdx.x; i < 784; i += 256) sw[i] = psi_w1[i];
  { int i = threadIdx.x;
    if (i < 256) { sw[800 + i] = psi_w2[i]; sw[1072 + i] = dec_w1[i]; }
    if (i < 16) {
      sw[784 + i] = psi_b1[i];
      sw[1056 + i] = psi_b2[i];
      sw[1328 + i] = dec_b1[i];
      sw[1344 + i] = dec_w2[i];
    }
    if (i == 0) sw[1360] = dec_b2[0];
  }
  __syncthreads();

  int n = blockIdx.x * 256 + threadIdx.x;
  if (n >= NN) return;

  float hv[DD], mt[DD], mf[DD];
  load16(h + (size_t)n * DD, hv);
  load16(mto + (size_t)n * DD, mt);
  load16(mfr + (size_t)n * DD, mf);
  float p = prb[n];

  float hid[DD];
  #pragma unroll
  for (int j = 0; j < DD; ++j) hid[j] = sw[784 + j];
  #pragma unroll
  for (int i = 0; i < DD; ++i) {
    float x = hv[i];
    #pragma unroll
    for (int j = 0; j < DD; ++j) hid[j] = fmaf(x, sw[i * DD + j], hid[j]);
  }
  #pragma unroll
  for (int i = 0; i < DD; ++i) {
    float x = mt[i];
    #pragma unroll
    for (int j = 0; j < DD; ++j) hid[j] = fmaf(x, sw[(DD + i) * DD + j], hid[j]);
  }
  #pragma unroll
  for (int i = 0; i < DD; ++i) {
    float x = mf[i];
    #pragma unroll
    for (int j = 0; j < DD; ++j) hid[j] = fmaf(x, sw[(2 * DD + i) * DD + j], hid[j]);
  }
  #pragma unroll
  for (int j = 0; j < DD; ++j) hid[j] = fmaf(p, sw[48 * DD + j], hid[j]);
  #pragma unroll
  for (int j = 0; j < DD; ++j) hid[j] = fmaxf(hid[j], 0.0f);

  float hnew[DD];
  #pragma unroll
  for (int j = 0; j < DD; ++j) hnew[j] = sw[1056 + j];
  #pragma unroll
  for (int i = 0; i < DD; ++i) {
    float x = hid[i];
    #pragma unroll
    for (int j = 0; j < DD; ++j) hnew[j] = fmaf(x, sw[800 + i * DD + j], hnew[j]);
  }
  #pragma unroll
  for (int j = 0; j < DD; ++j) hnew[j] = fmaf(ALPHA, hnew[j], hv[j]);
  store16(h + (size_t)n * DD, hnew);

  float hid2[DD];
  #pragma unroll
  for (int j = 0; j < DD; ++j) hid2[j] = sw[1328 + j];
  #pragma unroll
  for (int i = 0; i < DD; ++i) {
    float x = hnew[i];
    #pragma unroll
    for (int j = 0; j < DD; ++j) hid2[j] = fmaf(x, sw[1072 + i * DD + j], hid2[j]);
  }
  float uo = sw[1360];
  #pragma unroll
  for (int i = 0; i < DD; ++i) uo += fmaxf(hid2[i], 0.0f) * sw[1344 + i];
  u[n] = uo;
}

// ---------------------------------------------------------------------------
// Fused Au + loss
// ---------------------------------------------------------------------------
__global__ __launch_bounds__(256) void au_loss_kernel(
    const int* __restrict__ base_src, const float2* __restrict__ pay_au,
    const float* __restrict__ u, const float* __restrict__ y,
    float w, float* __restrict__ loss)
{
  int n = blockIdx.x * 256 + threadIdx.x;
  float acc = 0.0f;
  if (n < NN) {
    float au = 0.0f;
    int beg = base_src[n], end = base_src[n + 1];
    for (int i = beg; i < end; ++i) {
      float2 q = pay_au[i];
      au = fmaf(q.y, u[__float_as_int(q.x)], au);
    }
    float dlt = au - y[n];
    acc = dlt * dlt;
  }
  #pragma unroll
  for (int off = 32; off > 0; off >>= 1) acc += __shfl_down(acc, off);
  __shared__ float ss[4];
  int lane = threadIdx.x & 63, wid = threadIdx.x >> 6;
  if (lane == 0) ss[wid] = acc;
  __syncthreads();
  if (threadIdx.x == 0) {
    atomicAdd(loss, (ss[0] + ss[1] + ss[2] + ss[3]) * w);
  }
}

extern "C" void kernel_launch(void* const* d_in, const int* in_sizes, int n_in,
                              void* d_out, int out_size, void* d_ws, size_t ws_size,
                              hipStream_t stream) {
  const int*   ei        = (const int*)d_in[0];
  const float* ea        = (const float*)d_in[1];
  const float* a_ij      = (const float*)d_in[2];
  const float* prb       = (const float*)d_in[3];
  const float* y         = (const float*)d_in[5];
  const float* phi_to_w1 = (const float*)d_in[6];
  const float* phi_to_b1 = (const float*)d_in[7];
  const float* phi_to_w2 = (const float*)d_in[8];
  const float* phi_to_b2 = (const float*)d_in[9];
  const float* phi_fr_w1 = (const float*)d_in[10];
  const float* phi_fr_b1 = (const float*)d_in[11];
  const float* phi_fr_w2 = (const float*)d_in[12];
  const float* phi_fr_b2 = (const float*)d_in[13];
  const float* psi_w1    = (const float*)d_in[14];
  const float* psi_b1    = (const float*)d_in[15];
  const float* psi_w2    = (const float*)d_in[16];
  const float* psi_b2    = (const float*)d_in[17];
  const float* dec_w1    = (const float*)d_in[18];
  const float* dec_b1    = (const float*)d_in[19];
  const float* dec_w2    = (const float*)d_in[20];
  const float* dec_b2    = (const float*)d_in[21];

  float* out_u    = (float*)d_out;
  float* out_loss = out_u + NN;

  char* wp = (char*)d_ws;
  auto carve = [&](size_t bytes) { void* p = (void*)wp; wp += (bytes + 15) & ~(size_t)15; return p; };
  float4* pay_dst  = (float4*)carve((size_t)NE * 16);
  float4* pay_src  = (float4*)carve((size_t)NE * 16);
  float2* pay_au   = (float2*)carve((size_t)NE * 8);
  float*  h        = (float*)carve((size_t)NN * DD * 4);
  float*  mto      = (float*)carve((size_t)NN * DD * 4);
  float*  mfr      = (float*)carve((size_t)NN * DD * 4);
  int*    rank_dst = (int*)carve((size_t)NE * 4);
  int*    rank_src = (int*)carve((size_t)NE * 4);
  int*    base_dst = (int*)carve((size_t)(NN + 1) * 4);
  int*    base_src = (int*)carve((size_t)(NN + 1) * 4);
  int*    hist_dst = (int*)carve((size_t)NN * 4);
  int*    hist_src = (int*)carve((size_t)NN * 4);
  int*    sums     = (int*)carve(256 * 4);

  hipMemsetAsync(h, 0, (size_t)NN * DD * 4, stream);
  hipMemsetAsync(out_loss, 0, 4, stream);
  hipMemsetAsync(hist_dst, 0, (size_t)NN * 4, stream);
  hipMemsetAsync(hist_src, 0, (size_t)NN * 4, stream);

  const int EB = (NE + 255) / 256;          // 3125
  const int NB = (NN + 255) / 256;          // 391
  const int SB1 = (NN + 1023) / 1024;       // 98

  hist_kernel<<<EB, 256, 0, stream>>>(ei, hist_dst, hist_src, rank_dst, rank_src);

  scan1_kernel<<<SB1, 256, 0, stream>>>(hist_dst, base_dst, sums, NN);
  scan2_kernel<<<1, 256, 0, stream>>>(sums, SB1, base_dst + NN);
  scan3_kernel<<<NB, 256, 0, stream>>>(base_dst, sums, NN);

  scan1_kernel<<<SB1, 256, 0, stream>>>(hist_src, base_src, sums, NN);
  scan2_kernel<<<1, 256, 0, stream>>>(sums, SB1, base_src + NN);
  scan3_kernel<<<NB, 256, 0, stream>>>(base_src, sums, NN);

  scatter_kernel<<<EB, 256, 0, stream>>>(ei, ea, a_ij, base_dst, base_src,
                                         rank_dst, rank_src, pay_dst, pay_src, pay_au);

  const float gw[3] = {0.81f, 0.9f, 1.0f};  // gamma^(K-1-t)
  const int GB = (2 * NN + 255) / 256;      // 782

  for (int t = 0; t < 3; ++t) {
    gather_kernel<<<GB, 256, 0, stream>>>(
        h, pay_dst, pay_src, base_dst, base_src,
        phi_to_w1 + t * 560, phi_to_b1 + t * 16, phi_to_w2 + t * 256, phi_to_b2 + t * 16,
        phi_fr_w1 + t * 560, phi_fr_b1 + t * 16, phi_fr_w2 + t * 256, phi_fr_b2 + t * 16,
        mto, mfr);

    node_kernel<<<NB, 256, 0, stream>>>(
        h, mto, mfr, prb,
        psi_w1 + t * 784, psi_b1 + t * 16, psi_w2 + t * 256, psi_b2 + t * 16,
        dec_w1 + t * 256, dec_b1 + t * 16, dec_w2 + t * 16, dec_b2 + t,
        out_u);

    au_loss_kernel<<<NB, 256, 0, stream>>>(base_src, pay_au, out_u, y,
                                           gw[t] / (float)NN, out_loss);
  }
}

// Round 4
// 354.617 us; speedup vs baseline: 11.8976x; 1.3696x over previous
//
#include <hip/hip_runtime.h>

#define NN 100000
#define NE 800000
#define DD 16
#define ALPHA 0.1f

__device__ __forceinline__ void load16(const float* __restrict__ p, float* r) {
  float4 v0 = *(const float4*)(p + 0);
  float4 v1 = *(const float4*)(p + 4);
  float4 v2 = *(const float4*)(p + 8);
  float4 v3 = *(const float4*)(p + 12);
  r[0]=v0.x; r[1]=v0.y; r[2]=v0.z; r[3]=v0.w;
  r[4]=v1.x; r[5]=v1.y; r[6]=v1.z; r[7]=v1.w;
  r[8]=v2.x; r[9]=v2.y; r[10]=v2.z; r[11]=v2.w;
  r[12]=v3.x; r[13]=v3.y; r[14]=v3.z; r[15]=v3.w;
}

__device__ __forceinline__ void store16(float* __restrict__ p, const float* r) {
  *(float4*)(p + 0)  = make_float4(r[0], r[1], r[2], r[3]);
  *(float4*)(p + 4)  = make_float4(r[4], r[5], r[6], r[7]);
  *(float4*)(p + 8)  = make_float4(r[8], r[9], r[10], r[11]);
  *(float4*)(p + 12) = make_float4(r[12], r[13], r[14], r[15]);
}

// ---------------------------------------------------------------------------
// hist + rank
// ---------------------------------------------------------------------------
__global__ __launch_bounds__(256) void hist_kernel(
    const int* __restrict__ ei,
    int* __restrict__ hist_dst, int* __restrict__ hist_src,
    int* __restrict__ rank_dst, int* __restrict__ rank_src)
{
  int e = blockIdx.x * 256 + threadIdx.x;
  if (e >= NE) return;
  int s = ei[e];
  int d = ei[NE + e];
  rank_src[e] = atomicAdd(&hist_src[s], 1);
  rank_dst[e] = atomicAdd(&hist_dst[d], 1);
}

__global__ __launch_bounds__(256) void scan1_kernel(
    const int* __restrict__ in, int* __restrict__ out, int* __restrict__ sums, int L)
{
  __shared__ int sh[256];
  int t = threadIdx.x;
  int i0 = blockIdx.x * 1024 + t * 4;
  int v0 = (i0 + 0 < L) ? in[i0 + 0] : 0;
  int v1 = (i0 + 1 < L) ? in[i0 + 1] : 0;
  int v2 = (i0 + 2 < L) ? in[i0 + 2] : 0;
  int v3 = (i0 + 3 < L) ? in[i0 + 3] : 0;
  int tot = v0 + v1 + v2 + v3;
  sh[t] = tot;
  __syncthreads();
  int val = tot;
  for (int off = 1; off < 256; off <<= 1) {
    int x = (t >= off) ? sh[t - off] : 0;
    __syncthreads();
    val += x; sh[t] = val;
    __syncthreads();
  }
  if (t == 255) sums[blockIdx.x] = val;
  int run = val - tot;
  if (i0 + 0 < L) out[i0 + 0] = run; run += v0;
  if (i0 + 1 < L) out[i0 + 1] = run; run += v1;
  if (i0 + 2 < L) out[i0 + 2] = run; run += v2;
  if (i0 + 3 < L) out[i0 + 3] = run;
}

__global__ __launch_bounds__(256) void scan2_kernel(
    int* __restrict__ sums, int nb, int* __restrict__ out_total)
{
  __shared__ int sh[256];
  int t = threadIdx.x;
  int v = (t < nb) ? sums[t] : 0;
  sh[t] = v;
  __syncthreads();
  int val = v;
  for (int off = 1; off < 256; off <<= 1) {
    int x = (t >= off) ? sh[t - off] : 0;
    __syncthreads();
    val += x; sh[t] = val;
    __syncthreads();
  }
  if (t < nb) sums[t] = val - v;
  if (t == 255) *out_total = val;
}

__global__ __launch_bounds__(256) void scan3_kernel(
    int* __restrict__ out, const int* __restrict__ sums, int L)
{
  int i = blockIdx.x * 256 + threadIdx.x;
  if (i < L) out[i] += sums[i >> 10];
}

// atomic-free payload scatter
__global__ __launch_bounds__(256) void scatter_kernel(
    const int* __restrict__ ei, const float* __restrict__ ea, const float* __restrict__ a,
    const int* __restrict__ base_dst, const int* __restrict__ base_src,
    const int* __restrict__ rank_dst, const int* __restrict__ rank_src,
    float4* __restrict__ pay_dst, float4* __restrict__ pay_src, float2* __restrict__ pay_au)
{
  int e = blockIdx.x * 256 + threadIdx.x;
  if (e >= NE) return;
  int s = ei[e];
  int d = ei[NE + e];
  float e0 = ea[3 * (size_t)e], e1 = ea[3 * (size_t)e + 1], e2 = ea[3 * (size_t)e + 2];
  int sl = (s == d);
  int pd = base_dst[d] + rank_dst[e];
  pay_dst[pd] = make_float4(__int_as_float(sl ? -1 : s), e0, e1, e2);
  int ps = base_src[s] + rank_src[e];
  pay_src[ps] = make_float4(__int_as_float(sl ? -1 : d), e0, e1, e2);
  pay_au[ps] = make_float2(__int_as_float(d), a[e]);
}

// ---------------------------------------------------------------------------
// Gather: 4-lane subgroup per (node, direction). Lanes stride the edge list,
// accumulate sum(relu(hid)) privately, shfl_xor-reduce, then each lane emits
// 4 of the 16 layer-2 outputs (coalesced float4 stores).
// FIRST=true (t==0): h == 0 exactly -> no h loads at all.
// ---------------------------------------------------------------------------
template<bool FIRST>
__global__ __launch_bounds__(256) void gather_kernel(
    const float* __restrict__ h,
    const float4* __restrict__ pay_dst, const float4* __restrict__ pay_src,
    const int* __restrict__ base_dst, const int* __restrict__ base_src,
    const float* __restrict__ to_w1, const float* __restrict__ to_b1,
    const float* __restrict__ to_w2, const float* __restrict__ to_b2,
    const float* __restrict__ fr_w1, const float* __restrict__ fr_b1,
    const float* __restrict__ fr_w2, const float* __restrict__ fr_b2,
    float* __restrict__ mto, float* __restrict__ mfr)
{
  // per half (848 floats): w1[560] b1[16] w2[256] b2[16]
  __shared__ float sw[1696];
  for (int i = threadIdx.x; i < 560; i += 256) { sw[i] = to_w1[i]; sw[848 + i] = fr_w1[i]; }
  { int i = threadIdx.x;
    if (i < 256) { sw[576 + i] = to_w2[i]; sw[848 + 576 + i] = fr_w2[i]; }
    if (i < 16) {
      sw[560 + i] = to_b1[i];
      sw[832 + i] = to_b2[i];
      sw[848 + 560 + i] = fr_b1[i];
      sw[848 + 832 + i] = fr_b2[i];
    }
  }
  __syncthreads();

  int gid = (blockIdx.x * 256 + threadIdx.x) >> 2;   // group = (node, dir)
  int l = threadIdx.x & 3;
  if (gid >= 2 * NN) return;
  int dir = (gid >= NN) ? 1 : 0;      // 0 = mess_to (by dst), 1 = mess_from (by src)
  int n = gid - (dir ? NN : 0);

  const float* w1 = sw + (dir ? 848 : 0);
  const float* b1 = w1 + 560;
  const float* w2 = w1 + 576;
  const float* b2 = w1 + 832;
  const float4* pay = dir ? pay_src : pay_dst;
  const int* base = dir ? base_src : base_dst;

  // hoisted own-feature projection p1 (redundant across the 4 lanes)
  float p1[DD];
  #pragma unroll
  for (int j = 0; j < DD; ++j) p1[j] = b1[j];
  if (!FIRST) {
    float hn[DD];
    load16(h + (size_t)n * DD, hn);
    #pragma unroll
    for (int i = 0; i < DD; ++i) {
      float x = hn[i];
      #pragma unroll
      for (int j = 0; j < DD; ++j) p1[j] = fmaf(x, w1[i * DD + j], p1[j]);
    }
  }

  float hs_[DD];
  #pragma unroll
  for (int j = 0; j < DD; ++j) hs_[j] = 0.0f;
  int cnt = 0;

  int beg = base[n], end = base[n + 1];
  for (int i = beg + l; i < end; i += 4) {
    float4 q = pay[i];
    int nb = __float_as_int(q.x);
    if (nb >= 0) {
      float hid[DD];
      #pragma unroll
      for (int j = 0; j < DD; ++j)
        hid[j] = fmaf(q.y, w1[32 * DD + j],
                 fmaf(q.z, w1[33 * DD + j],
                 fmaf(q.w, w1[34 * DD + j], p1[j])));
      if (!FIRST) {
        float hb[DD];
        load16(h + (size_t)nb * DD, hb);
        #pragma unroll
        for (int k = 0; k < DD; ++k) {
          float x = hb[k];
          #pragma unroll
          for (int j = 0; j < DD; ++j) hid[j] = fmaf(x, w1[(DD + k) * DD + j], hid[j]);
        }
      }
      #pragma unroll
      for (int j = 0; j < DD; ++j) hs_[j] += fmaxf(hid[j], 0.0f);
      ++cnt;
    }
  }

  // reduce sum(relu) + count across the 4-lane subgroup
  #pragma unroll
  for (int j = 0; j < DD; ++j) {
    hs_[j] += __shfl_xor(hs_[j], 1, 64);
    hs_[j] += __shfl_xor(hs_[j], 2, 64);
  }
  cnt += __shfl_xor(cnt, 1, 64);
  cnt += __shfl_xor(cnt, 2, 64);

  // layer 2 once per group, feature-split: lane l emits outputs [4l, 4l+4)
  float c = (float)cnt;
  float m0 = c * b2[4 * l + 0];
  float m1 = c * b2[4 * l + 1];
  float m2 = c * b2[4 * l + 2];
  float m3 = c * b2[4 * l + 3];
  #pragma unroll
  for (int k = 0; k < DD; ++k) {
    float x = hs_[k];
    const float* wr = w2 + k * DD + 4 * l;
    m0 = fmaf(x, wr[0], m0);
    m1 = fmaf(x, wr[1], m1);
    m2 = fmaf(x, wr[2], m2);
    m3 = fmaf(x, wr[3], m3);
  }
  float* dst = (dir ? mfr : mto) + (size_t)n * DD + 4 * l;
  *(float4*)dst = make_float4(m0, m1, m2, m3);
}

// ---------------------------------------------------------------------------
// Node kernel
// ---------------------------------------------------------------------------
__global__ __launch_bounds__(256) void node_kernel(
    float* __restrict__ h, const float* __restrict__ mto, const float* __restrict__ mfr,
    const float* __restrict__ prb,
    const float* __restrict__ psi_w1, const float* __restrict__ psi_b1,
    const float* __restrict__ psi_w2, const float* __restrict__ psi_b2,
    const float* __restrict__ dec_w1, const float* __restrict__ dec_b1,
    const float* __restrict__ dec_w2, const float* __restrict__ dec_b2,
    float* __restrict__ u)
{
  __shared__ float sw[1361];
  for (int i = threadIdx.x; i < 784; i += 256) sw[i] = psi_w1[i];
  { int i = threadIdx.x;
    if (i < 256) { sw[800 + i] = psi_w2[i]; sw[1072 + i] = dec_w1[i]; }
    if (i < 16) {
      sw[784 + i] = psi_b1[i];
      sw[1056 + i] = psi_b2[i];
      sw[1328 + i] = dec_b1[i];
      sw[1344 + i] = dec_w2[i];
    }
    if (i == 0) sw[1360] = dec_b2[0];
  }
  __syncthreads();

  int n = blockIdx.x * 256 + threadIdx.x;
  if (n >= NN) return;

  float hv[DD], mt[DD], mf[DD];
  load16(h + (size_t)n * DD, hv);
  load16(mto + (size_t)n * DD, mt);
  load16(mfr + (size_t)n * DD, mf);
  float p = prb[n];

  float hid[DD];
  #pragma unroll
  for (int j = 0; j < DD; ++j) hid[j] = sw[784 + j];
  #pragma unroll
  for (int i = 0; i < DD; ++i) {
    float x = hv[i];
    #pragma unroll
    for (int j = 0; j < DD; ++j) hid[j] = fmaf(x, sw[i * DD + j], hid[j]);
  }
  #pragma unroll
  for (int i = 0; i < DD; ++i) {
    float x = mt[i];
    #pragma unroll
    for (int j = 0; j < DD; ++j) hid[j] = fmaf(x, sw[(DD + i) * DD + j], hid[j]);
  }
  #pragma unroll
  for (int i = 0; i < DD; ++i) {
    float x = mf[i];
    #pragma unroll
    for (int j = 0; j < DD; ++j) hid[j] = fmaf(x, sw[(2 * DD + i) * DD + j], hid[j]);
  }
  #pragma unroll
  for (int j = 0; j < DD; ++j) hid[j] = fmaf(p, sw[48 * DD + j], hid[j]);
  #pragma unroll
  for (int j = 0; j < DD; ++j) hid[j] = fmaxf(hid[j], 0.0f);

  float hnew[DD];
  #pragma unroll
  for (int j = 0; j < DD; ++j) hnew[j] = sw[1056 + j];
  #pragma unroll
  for (int i = 0; i < DD; ++i) {
    float x = hid[i];
    #pragma unroll
    for (int j = 0; j < DD; ++j) hnew[j] = fmaf(x, sw[800 + i * DD + j], hnew[j]);
  }
  #pragma unroll
  for (int j = 0; j < DD; ++j) hnew[j] = fmaf(ALPHA, hnew[j], hv[j]);
  store16(h + (size_t)n * DD, hnew);

  float hid2[DD];
  #pragma unroll
  for (int j = 0; j < DD; ++j) hid2[j] = sw[1328 + j];
  #pragma unroll
  for (int i = 0; i < DD; ++i) {
    float x = hnew[i];
    #pragma unroll
    for (int j = 0; j < DD; ++j) hid2[j] = fmaf(x, sw[1072 + i * DD + j], hid2[j]);
  }
  float uo = sw[1360];
  #pragma unroll
  for (int i = 0; i < DD; ++i) uo += fmaxf(hid2[i], 0.0f) * sw[1344 + i];
  u[n] = uo;
}

// ---------------------------------------------------------------------------
// Fused Au + loss
// ---------------------------------------------------------------------------
__global__ __launch_bounds__(256) void au_loss_kernel(
    const int* __restrict__ base_src, const float2* __restrict__ pay_au,
    const float* __restrict__ u, const float* __restrict__ y,
    float w, float* __restrict__ loss)
{
  int n = blockIdx.x * 256 + threadIdx.x;
  float acc = 0.0f;
  if (n < NN) {
    float au = 0.0f;
    int beg = base_src[n], end = base_src[n + 1];
    for (int i = beg; i < end; ++i) {
      float2 q = pay_au[i];
      au = fmaf(q.y, u[__float_as_int(q.x)], au);
    }
    float dlt = au - y[n];
    acc = dlt * dlt;
  }
  #pragma unroll
  for (int off = 32; off > 0; off >>= 1) acc += __shfl_down(acc, off);
  __shared__ float ss[4];
  int lane = threadIdx.x & 63, wid = threadIdx.x >> 6;
  if (lane == 0) ss[wid] = acc;
  __syncthreads();
  if (threadIdx.x == 0) {
    atomicAdd(loss, (ss[0] + ss[1] + ss[2] + ss[3]) * w);
  }
}

extern "C" void kernel_launch(void* const* d_in, const int* in_sizes, int n_in,
                              void* d_out, int out_size, void* d_ws, size_t ws_size,
                              hipStream_t stream) {
  const int*   ei        = (const int*)d_in[0];
  const float* ea        = (const float*)d_in[1];
  const float* a_ij      = (const float*)d_in[2];
  const float* prb       = (const float*)d_in[3];
  const float* y         = (const float*)d_in[5];
  const float* phi_to_w1 = (const float*)d_in[6];
  const float* phi_to_b1 = (const float*)d_in[7];
  const float* phi_to_w2 = (const float*)d_in[8];
  const float* phi_to_b2 = (const float*)d_in[9];
  const float* phi_fr_w1 = (const float*)d_in[10];
  const float* phi_fr_b1 = (const float*)d_in[11];
  const float* phi_fr_w2 = (const float*)d_in[12];
  const float* phi_fr_b2 = (const float*)d_in[13];
  const float* psi_w1    = (const float*)d_in[14];
  const float* psi_b1    = (const float*)d_in[15];
  const float* psi_w2    = (const float*)d_in[16];
  const float* psi_b2    = (const float*)d_in[17];
  const float* dec_w1    = (const float*)d_in[18];
  const float* dec_b1    = (const float*)d_in[19];
  const float* dec_w2    = (const float*)d_in[20];
  const float* dec_b2    = (const float*)d_in[21];

  float* out_u    = (float*)d_out;
  float* out_loss = out_u + NN;

  char* wp = (char*)d_ws;
  auto carve = [&](size_t bytes) { void* p = (void*)wp; wp += (bytes + 15) & ~(size_t)15; return p; };
  float4* pay_dst  = (float4*)carve((size_t)NE * 16);
  float4* pay_src  = (float4*)carve((size_t)NE * 16);
  float2* pay_au   = (float2*)carve((size_t)NE * 8);
  float*  h        = (float*)carve((size_t)NN * DD * 4);
  float*  mto      = (float*)carve((size_t)NN * DD * 4);
  float*  mfr      = (float*)carve((size_t)NN * DD * 4);
  int*    rank_dst = (int*)carve((size_t)NE * 4);
  int*    rank_src = (int*)carve((size_t)NE * 4);
  int*    base_dst = (int*)carve((size_t)(NN + 1) * 4);
  int*    base_src = (int*)carve((size_t)(NN + 1) * 4);
  int*    hist_dst = (int*)carve((size_t)NN * 4);
  int*    hist_src = (int*)carve((size_t)NN * 4);
  int*    sums     = (int*)carve(256 * 4);

  hipMemsetAsync(h, 0, (size_t)NN * DD * 4, stream);
  hipMemsetAsync(out_loss, 0, 4, stream);
  hipMemsetAsync(hist_dst, 0, (size_t)NN * 4, stream);
  hipMemsetAsync(hist_src, 0, (size_t)NN * 4, stream);

  const int EB = (NE + 255) / 256;          // 3125
  const int NB = (NN + 255) / 256;          // 391
  const int SB1 = (NN + 1023) / 1024;       // 98
  const int GB4 = (2 * NN * 4 + 255) / 256; // 3125

  hist_kernel<<<EB, 256, 0, stream>>>(ei, hist_dst, hist_src, rank_dst, rank_src);

  scan1_kernel<<<SB1, 256, 0, stream>>>(hist_dst, base_dst, sums, NN);
  scan2_kernel<<<1, 256, 0, stream>>>(sums, SB1, base_dst + NN);
  scan3_kernel<<<NB, 256, 0, stream>>>(base_dst, sums, NN);

  scan1_kernel<<<SB1, 256, 0, stream>>>(hist_src, base_src, sums, NN);
  scan2_kernel<<<1, 256, 0, stream>>>(sums, SB1, base_src + NN);
  scan3_kernel<<<NB, 256, 0, stream>>>(base_src, sums, NN);

  scatter_kernel<<<EB, 256, 0, stream>>>(ei, ea, a_ij, base_dst, base_src,
                                         rank_dst, rank_src, pay_dst, pay_src, pay_au);

  const float gw[3] = {0.81f, 0.9f, 1.0f};  // gamma^(K-1-t)

  for (int t = 0; t < 3; ++t) {
    if (t == 0) {
      gather_kernel<true><<<GB4, 256, 0, stream>>>(
          h, pay_dst, pay_src, base_dst, base_src,
          phi_to_w1, phi_to_b1, phi_to_w2, phi_to_b2,
          phi_fr_w1, phi_fr_b1, phi_fr_w2, phi_fr_b2,
          mto, mfr);
    } else {
      gather_kernel<false><<<GB4, 256, 0, stream>>>(
          h, pay_dst, pay_src, base_dst, base_src,
          phi_to_w1 + t * 560, phi_to_b1 + t * 16, phi_to_w2 + t * 256, phi_to_b2 + t * 16,
          phi_fr_w1 + t * 560, phi_fr_b1 + t * 16, phi_fr_w2 + t * 256, phi_fr_b2 + t * 16,
          mto, mfr);
    }

    node_kernel<<<NB, 256, 0, stream>>>(
        h, mto, mfr, prb,
        psi_w1 + t * 784, psi_b1 + t * 16, psi_w2 + t * 256, psi_b2 + t * 16,
        dec_w1 + t * 256, dec_b1 + t * 16, dec_w2 + t * 16, dec_b2 + t,
        out_u);

    au_loss_kernel<<<NB, 256, 0, stream>>>(base_src, pay_au, out_u, y,
                                           gw[t] / (float)NN, out_loss);
  }
}

// Round 5
// 341.808 us; speedup vs baseline: 12.3435x; 1.0375x over previous
//
#include <hip/hip_runtime.h>

#define NN 100000
#define NE 800000
#define DD 16
#define ALPHA 0.1f

__device__ __forceinline__ void load16(const float* __restrict__ p, float* r) {
  float4 v0 = *(const float4*)(p + 0);
  float4 v1 = *(const float4*)(p + 4);
  float4 v2 = *(const float4*)(p + 8);
  float4 v3 = *(const float4*)(p + 12);
  r[0]=v0.x; r[1]=v0.y; r[2]=v0.z; r[3]=v0.w;
  r[4]=v1.x; r[5]=v1.y; r[6]=v1.z; r[7]=v1.w;
  r[8]=v2.x; r[9]=v2.y; r[10]=v2.z; r[11]=v2.w;
  r[12]=v3.x; r[13]=v3.y; r[14]=v3.z; r[15]=v3.w;
}

__device__ __forceinline__ void store16(float* __restrict__ p, const float* r) {
  *(float4*)(p + 0)  = make_float4(r[0], r[1], r[2], r[3]);
  *(float4*)(p + 4)  = make_float4(r[4], r[5], r[6], r[7]);
  *(float4*)(p + 8)  = make_float4(r[8], r[9], r[10], r[11]);
  *(float4*)(p + 12) = make_float4(r[12], r[13], r[14], r[15]);
}

__device__ __forceinline__ unsigned f2bf(float x) {  // RNE f32 -> bf16 bits
  unsigned b = __float_as_uint(x);
  return (b + 0x7FFFu + ((b >> 16) & 1u)) >> 16;
}

// ---------------------------------------------------------------------------
// hist + rank over unified [in-degree | out-degree] histogram of length 2N
// ---------------------------------------------------------------------------
__global__ __launch_bounds__(256) void hist_kernel(
    const int* __restrict__ ei, int* __restrict__ hist,
    int* __restrict__ rank_dst, int* __restrict__ rank_src)
{
  int e = blockIdx.x * 256 + threadIdx.x;
  if (e >= NE) return;
  int s = ei[e];
  int d = ei[NE + e];
  rank_dst[e] = atomicAdd(&hist[d], 1);
  rank_src[e] = atomicAdd(&hist[NN + s], 1);
}

__global__ __launch_bounds__(256) void scan1_kernel(
    const int* __restrict__ in, int* __restrict__ out, int* __restrict__ sums, int L)
{
  __shared__ int sh[256];
  int t = threadIdx.x;
  int i0 = blockIdx.x * 1024 + t * 4;
  int v0 = (i0 + 0 < L) ? in[i0 + 0] : 0;
  int v1 = (i0 + 1 < L) ? in[i0 + 1] : 0;
  int v2 = (i0 + 2 < L) ? in[i0 + 2] : 0;
  int v3 = (i0 + 3 < L) ? in[i0 + 3] : 0;
  int tot = v0 + v1 + v2 + v3;
  sh[t] = tot;
  __syncthreads();
  int val = tot;
  for (int off = 1; off < 256; off <<= 1) {
    int x = (t >= off) ? sh[t - off] : 0;
    __syncthreads();
    val += x; sh[t] = val;
    __syncthreads();
  }
  if (t == 255) sums[blockIdx.x] = val;
  int run = val - tot;
  if (i0 + 0 < L) out[i0 + 0] = run; run += v0;
  if (i0 + 1 < L) out[i0 + 1] = run; run += v1;
  if (i0 + 2 < L) out[i0 + 2] = run; run += v2;
  if (i0 + 3 < L) out[i0 + 3] = run;
}

__global__ __launch_bounds__(256) void scan2_kernel(
    int* __restrict__ sums, int nb, int* __restrict__ out_total)
{
  __shared__ int sh[256];
  int t = threadIdx.x;
  int v = (t < nb) ? sums[t] : 0;
  sh[t] = v;
  __syncthreads();
  int val = v;
  for (int off = 1; off < 256; off <<= 1) {
    int x = (t >= off) ? sh[t - off] : 0;
    __syncthreads();
    val += x; sh[t] = val;
    __syncthreads();
  }
  if (t < nb) sums[t] = val - v;
  if (t == 255) *out_total = val;   // = 2*NE sentinel at base[2N]
}

__global__ __launch_bounds__(256) void scan3_kernel(
    int* __restrict__ out, const int* __restrict__ sums, int L)
{
  int i = blockIdx.x * 256 + threadIdx.x;
  if (i < L) out[i] += sums[i >> 10];
}

// atomic-free payload scatter into unified pay[2*NE]
__global__ __launch_bounds__(256) void scatter_kernel(
    const int* __restrict__ ei, const float* __restrict__ ea, const float* __restrict__ a,
    const int* __restrict__ base,
    const int* __restrict__ rank_dst, const int* __restrict__ rank_src,
    float4* __restrict__ pay, float2* __restrict__ pay_au)
{
  int e = blockIdx.x * 256 + threadIdx.x;
  if (e >= NE) return;
  int s = ei[e];
  int d = ei[NE + e];
  float e0 = ea[3 * (size_t)e], e1 = ea[3 * (size_t)e + 1], e2 = ea[3 * (size_t)e + 2];
  int sl = (s == d);
  int pd = base[d] + rank_dst[e];
  pay[pd] = make_float4(__int_as_float(sl ? -1 : s), e0, e1, e2);
  int ps = base[NN + s] + rank_src[e];
  pay[ps] = make_float4(__int_as_float(sl ? -1 : d), e0, e1, e2);
  pay_au[ps - NE] = make_float2(__int_as_float(d), a[e]);
}

// ---------------------------------------------------------------------------
// Gather (8-lane subgroup per (node,dir)) + optionally fused au_loss blocks.
//   blocks [0, gblocks)        : message gather
//   blocks [gblocks, grid)     : au_loss for iteration t-1 (reads prev u)
// FIRST=true: h==0 -> no h reads. Neighbor h read from bf16 shadow copy.
// ---------------------------------------------------------------------------
template<bool FIRST, bool WITH_AU>
__global__ __launch_bounds__(256) void gather_kernel(
    const float* __restrict__ h, const unsigned short* __restrict__ hb,
    const float4* __restrict__ pay, const int* __restrict__ base,
    const float* __restrict__ to_w1, const float* __restrict__ to_b1,
    const float* __restrict__ to_w2, const float* __restrict__ to_b2,
    const float* __restrict__ fr_w1, const float* __restrict__ fr_b1,
    const float* __restrict__ fr_w2, const float* __restrict__ fr_b2,
    float* __restrict__ mto, float* __restrict__ mfr, int gblocks,
    const float2* __restrict__ pay_au, const float* __restrict__ u,
    const float* __restrict__ y, float w, float* __restrict__ loss)
{
  if (WITH_AU && (int)blockIdx.x >= gblocks) {
    // ---- au_loss body ----
    int n = (blockIdx.x - gblocks) * 256 + threadIdx.x;
    float acc = 0.0f;
    if (n < NN) {
      float au = 0.0f;
      int beg = base[NN + n] - NE, end = base[NN + n + 1] - NE;
      for (int i = beg; i < end; ++i) {
        float2 q = pay_au[i];
        au = fmaf(q.y, u[__float_as_int(q.x)], au);
      }
      float dlt = au - y[n];
      acc = dlt * dlt;
    }
    #pragma unroll
    for (int off = 32; off > 0; off >>= 1) acc += __shfl_down(acc, off);
    __shared__ float ss[4];
    int lane = threadIdx.x & 63, wid = threadIdx.x >> 6;
    if (lane == 0) ss[wid] = acc;
    __syncthreads();
    if (threadIdx.x == 0) atomicAdd(loss, (ss[0] + ss[1] + ss[2] + ss[3]) * w);
    return;
  }

  // ---- gather body ----
  // per half (848 floats): w1[560] b1[16] w2[256] b2[16]
  __shared__ float sw[1696];
  for (int i = threadIdx.x; i < 560; i += 256) { sw[i] = to_w1[i]; sw[848 + i] = fr_w1[i]; }
  { int i = threadIdx.x;
    if (i < 256) { sw[576 + i] = to_w2[i]; sw[848 + 576 + i] = fr_w2[i]; }
    if (i < 16) {
      sw[560 + i] = to_b1[i];
      sw[832 + i] = to_b2[i];
      sw[848 + 560 + i] = fr_b1[i];
      sw[848 + 832 + i] = fr_b2[i];
    }
  }
  __syncthreads();

  int gid = (blockIdx.x * 256 + threadIdx.x) >> 3;   // (node, dir) group
  int l = threadIdx.x & 7;
  if (gid >= 2 * NN) return;
  int dir = (gid >= NN) ? 1 : 0;      // 0 = mess_to (dst-sorted half), 1 = mess_from
  int n = gid - (dir ? NN : 0);

  const float* w1 = sw + (dir ? 848 : 0);
  const float* b1 = w1 + 560;
  const float* w2 = w1 + 576;
  const float* b2 = w1 + 832;

  float p1[DD];
  #pragma unroll
  for (int j = 0; j < DD; ++j) p1[j] = b1[j];
  if (!FIRST) {
    float hn[DD];
    load16(h + (size_t)n * DD, hn);
    #pragma unroll
    for (int i = 0; i < DD; ++i) {
      float x = hn[i];
      #pragma unroll
      for (int j = 0; j < DD; ++j) p1[j] = fmaf(x, w1[i * DD + j], p1[j]);
    }
  }

  float hs_[DD];
  #pragma unroll
  for (int j = 0; j < DD; ++j) hs_[j] = 0.0f;
  int cnt = 0;

  int beg = base[gid], end = base[gid + 1];
  for (int i = beg + l; i < end; i += 8) {
    float4 q = pay[i];
    int nb = __float_as_int(q.x);
    if (nb >= 0) {
      float hid[DD];
      #pragma unroll
      for (int j = 0; j < DD; ++j)
        hid[j] = fmaf(q.y, w1[32 * DD + j],
                 fmaf(q.z, w1[33 * DD + j],
                 fmaf(q.w, w1[34 * DD + j], p1[j])));
      if (!FIRST) {
        uint4 qa = *(const uint4*)(hb + (size_t)nb * DD);
        uint4 qb = *(const uint4*)(hb + (size_t)nb * DD + 8);
        float hv[DD];
        hv[0]  = __uint_as_float(qa.x << 16); hv[1]  = __uint_as_float(qa.x & 0xFFFF0000u);
        hv[2]  = __uint_as_float(qa.y << 16); hv[3]  = __uint_as_float(qa.y & 0xFFFF0000u);
        hv[4]  = __uint_as_float(qa.z << 16); hv[5]  = __uint_as_float(qa.z & 0xFFFF0000u);
        hv[6]  = __uint_as_float(qa.w << 16); hv[7]  = __uint_as_float(qa.w & 0xFFFF0000u);
        hv[8]  = __uint_as_float(qb.x << 16); hv[9]  = __uint_as_float(qb.x & 0xFFFF0000u);
        hv[10] = __uint_as_float(qb.y << 16); hv[11] = __uint_as_float(qb.y & 0xFFFF0000u);
        hv[12] = __uint_as_float(qb.z << 16); hv[13] = __uint_as_float(qb.z & 0xFFFF0000u);
        hv[14] = __uint_as_float(qb.w << 16); hv[15] = __uint_as_float(qb.w & 0xFFFF0000u);
        #pragma unroll
        for (int k = 0; k < DD; ++k) {
          float x = hv[k];
          #pragma unroll
          for (int j = 0; j < DD; ++j) hid[j] = fmaf(x, w1[(DD + k) * DD + j], hid[j]);
        }
      }
      #pragma unroll
      for (int j = 0; j < DD; ++j) hs_[j] += fmaxf(hid[j], 0.0f);
      ++cnt;
    }
  }

  // reduce across the 8-lane subgroup
  #pragma unroll
  for (int j = 0; j < DD; ++j) {
    hs_[j] += __shfl_xor(hs_[j], 1, 64);
    hs_[j] += __shfl_xor(hs_[j], 2, 64);
    hs_[j] += __shfl_xor(hs_[j], 4, 64);
  }
  cnt += __shfl_xor(cnt, 1, 64);
  cnt += __shfl_xor(cnt, 2, 64);
  cnt += __shfl_xor(cnt, 4, 64);

  // layer 2 once per group, feature-split: lane l emits outputs [2l, 2l+2)
  float c = (float)cnt;
  float m0 = c * b2[2 * l + 0];
  float m1 = c * b2[2 * l + 1];
  #pragma unroll
  for (int k = 0; k < DD; ++k) {
    float x = hs_[k];
    m0 = fmaf(x, w2[k * DD + 2 * l + 0], m0);
    m1 = fmaf(x, w2[k * DD + 2 * l + 1], m1);
  }
  float* dst = (dir ? mfr : mto) + (size_t)n * DD + 2 * l;
  *(float2*)dst = make_float2(m0, m1);
}

// ---------------------------------------------------------------------------
// Node kernel: h += ALPHA * psi([h, mto, mfr, prb]); u = dec(h); hb = bf16(h)
// ---------------------------------------------------------------------------
__global__ __launch_bounds__(256) void node_kernel(
    float* __restrict__ h, unsigned short* __restrict__ hb,
    const float* __restrict__ mto, const float* __restrict__ mfr,
    const float* __restrict__ prb,
    const float* __restrict__ psi_w1, const float* __restrict__ psi_b1,
    const float* __restrict__ psi_w2, const float* __restrict__ psi_b2,
    const float* __restrict__ dec_w1, const float* __restrict__ dec_b1,
    const float* __restrict__ dec_w2, const float* __restrict__ dec_b2,
    float* __restrict__ u)
{
  __shared__ float sw[1361];
  for (int i = threadIdx.x; i < 784; i += 256) sw[i] = psi_w1[i];
  { int i = threadIdx.x;
    if (i < 256) { sw[800 + i] = psi_w2[i]; sw[1072 + i] = dec_w1[i]; }
    if (i < 16) {
      sw[784 + i] = psi_b1[i];
      sw[1056 + i] = psi_b2[i];
      sw[1328 + i] = dec_b1[i];
      sw[1344 + i] = dec_w2[i];
    }
    if (i == 0) sw[1360] = dec_b2[0];
  }
  __syncthreads();

  int n = blockIdx.x * 256 + threadIdx.x;
  if (n >= NN) return;

  float hv[DD], mt[DD], mf[DD];
  load16(h + (size_t)n * DD, hv);
  load16(mto + (size_t)n * DD, mt);
  load16(mfr + (size_t)n * DD, mf);
  float p = prb[n];

  float hid[DD];
  #pragma unroll
  for (int j = 0; j < DD; ++j) hid[j] = sw[784 + j];
  #pragma unroll
  for (int i = 0; i < DD; ++i) {
    float x = hv[i];
    #pragma unroll
    for (int j = 0; j < DD; ++j) hid[j] = fmaf(x, sw[i * DD + j], hid[j]);
  }
  #pragma unroll
  for (int i = 0; i < DD; ++i) {
    float x = mt[i];
    #pragma unroll
    for (int j = 0; j < DD; ++j) hid[j] = fmaf(x, sw[(DD + i) * DD + j], hid[j]);
  }
  #pragma unroll
  for (int i = 0; i < DD; ++i) {
    float x = mf[i];
    #pragma unroll
    for (int j = 0; j < DD; ++j) hid[j] = fmaf(x, sw[(2 * DD + i) * DD + j], hid[j]);
  }
  #pragma unroll
  for (int j = 0; j < DD; ++j) hid[j] = fmaf(p, sw[48 * DD + j], hid[j]);
  #pragma unroll
  for (int j = 0; j < DD; ++j) hid[j] = fmaxf(hid[j], 0.0f);

  float hnew[DD];
  #pragma unroll
  for (int j = 0; j < DD; ++j) hnew[j] = sw[1056 + j];
  #pragma unroll
  for (int i = 0; i < DD; ++i) {
    float x = hid[i];
    #pragma unroll
    for (int j = 0; j < DD; ++j) hnew[j] = fmaf(x, sw[800 + i * DD + j], hnew[j]);
  }
  #pragma unroll
  for (int j = 0; j < DD; ++j) hnew[j] = fmaf(ALPHA, hnew[j], hv[j]);
  store16(h + (size_t)n * DD, hnew);

  // bf16 shadow copy (RNE)
  uint4 pa, pb;
  pa.x = f2bf(hnew[0])  | (f2bf(hnew[1])  << 16);
  pa.y = f2bf(hnew[2])  | (f2bf(hnew[3])  << 16);
  pa.z = f2bf(hnew[4])  | (f2bf(hnew[5])  << 16);
  pa.w = f2bf(hnew[6])  | (f2bf(hnew[7])  << 16);
  pb.x = f2bf(hnew[8])  | (f2bf(hnew[9])  << 16);
  pb.y = f2bf(hnew[10]) | (f2bf(hnew[11]) << 16);
  pb.z = f2bf(hnew[12]) | (f2bf(hnew[13]) << 16);
  pb.w = f2bf(hnew[14]) | (f2bf(hnew[15]) << 16);
  *(uint4*)(hb + (size_t)n * DD)     = pa;
  *(uint4*)(hb + (size_t)n * DD + 8) = pb;

  float hid2[DD];
  #pragma unroll
  for (int j = 0; j < DD; ++j) hid2[j] = sw[1328 + j];
  #pragma unroll
  for (int i = 0; i < DD; ++i) {
    float x = hnew[i];
    #pragma unroll
    for (int j = 0; j < DD; ++j) hid2[j] = fmaf(x, sw[1072 + i * DD + j], hid2[j]);
  }
  float uo = sw[1360];
  #pragma unroll
  for (int i = 0; i < DD; ++i) uo += fmaxf(hid2[i], 0.0f) * sw[1344 + i];
  u[n] = uo;
}

extern "C" void kernel_launch(void* const* d_in, const int* in_sizes, int n_in,
                              void* d_out, int out_size, void* d_ws, size_t ws_size,
                              hipStream_t stream) {
  const int*   ei        = (const int*)d_in[0];
  const float* ea        = (const float*)d_in[1];
  const float* a_ij      = (const float*)d_in[2];
  const float* prb       = (const float*)d_in[3];
  const float* y         = (const float*)d_in[5];
  const float* phi_to_w1 = (const float*)d_in[6];
  const float* phi_to_b1 = (const float*)d_in[7];
  const float* phi_to_w2 = (const float*)d_in[8];
  const float* phi_to_b2 = (const float*)d_in[9];
  const float* phi_fr_w1 = (const float*)d_in[10];
  const float* phi_fr_b1 = (const float*)d_in[11];
  const float* phi_fr_w2 = (const float*)d_in[12];
  const float* phi_fr_b2 = (const float*)d_in[13];
  const float* psi_w1    = (const float*)d_in[14];
  const float* psi_b1    = (const float*)d_in[15];
  const float* psi_w2    = (const float*)d_in[16];
  const float* psi_b2    = (const float*)d_in[17];
  const float* dec_w1    = (const float*)d_in[18];
  const float* dec_b1    = (const float*)d_in[19];
  const float* dec_w2    = (const float*)d_in[20];
  const float* dec_b2    = (const float*)d_in[21];

  float* out_u    = (float*)d_out;
  float* out_loss = out_u + NN;

  char* wp = (char*)d_ws;
  auto carve = [&](size_t bytes) { void* p = (void*)wp; wp += (bytes + 15) & ~(size_t)15; return p; };
  float4* pay      = (float4*)carve((size_t)2 * NE * 16);       // [dst-sorted | src-sorted]
  float2* pay_au   = (float2*)carve((size_t)NE * 8);
  float*  h        = (float*)carve((size_t)NN * DD * 4);
  unsigned short* hb16 = (unsigned short*)carve((size_t)NN * DD * 2);
  float*  mto      = (float*)carve((size_t)NN * DD * 4);
  float*  mfr      = (float*)carve((size_t)NN * DD * 4);
  int*    rank_dst = (int*)carve((size_t)NE * 4);
  int*    rank_src = (int*)carve((size_t)NE * 4);
  int*    base     = (int*)carve((size_t)(2 * NN + 1) * 4);
  int*    hist     = (int*)carve((size_t)2 * NN * 4);
  int*    sums     = (int*)carve(256 * 4);

  hipMemsetAsync(h, 0, (size_t)NN * DD * 4, stream);
  hipMemsetAsync(out_loss, 0, 4, stream);
  hipMemsetAsync(hist, 0, (size_t)2 * NN * 4, stream);

  const int EB  = (NE + 255) / 256;             // 3125
  const int NB  = (NN + 255) / 256;             // 391
  const int L2N = 2 * NN;                       // 200000
  const int SB1 = (L2N + 1023) / 1024;          // 196
  const int SB3 = (L2N + 255) / 256;            // 782
  const int GB8 = (L2N * 8 + 255) / 256;        // 6250

  hist_kernel<<<EB, 256, 0, stream>>>(ei, hist, rank_dst, rank_src);
  scan1_kernel<<<SB1, 256, 0, stream>>>(hist, base, sums, L2N);
  scan2_kernel<<<1, 256, 0, stream>>>(sums, SB1, base + L2N);   // sentinel = 2*NE
  scan3_kernel<<<SB3, 256, 0, stream>>>(base, sums, L2N);
  scatter_kernel<<<EB, 256, 0, stream>>>(ei, ea, a_ij, base, rank_dst, rank_src,
                                         pay, pay_au);

  const float gw[3] = {0.81f, 0.9f, 1.0f};  // gamma^(K-1-t)

  // t = 0 (h == 0: no h reads)
  gather_kernel<true, false><<<GB8, 256, 0, stream>>>(
      h, hb16, pay, base,
      phi_to_w1, phi_to_b1, phi_to_w2, phi_to_b2,
      phi_fr_w1, phi_fr_b1, phi_fr_w2, phi_fr_b2,
      mto, mfr, GB8, pay_au, out_u, y, 0.0f, out_loss);
  node_kernel<<<NB, 256, 0, stream>>>(
      h, hb16, mto, mfr, prb,
      psi_w1, psi_b1, psi_w2, psi_b2,
      dec_w1, dec_b1, dec_w2, dec_b2, out_u);

  // t = 1, 2: gather(t) fused with au_loss(t-1)
  for (int t = 1; t < 3; ++t) {
    gather_kernel<false, true><<<GB8 + NB, 256, 0, stream>>>(
        h, hb16, pay, base,
        phi_to_w1 + t * 560, phi_to_b1 + t * 16, phi_to_w2 + t * 256, phi_to_b2 + t * 16,
        phi_fr_w1 + t * 560, phi_fr_b1 + t * 16, phi_fr_w2 + t * 256, phi_fr_b2 + t * 16,
        mto, mfr, GB8, pay_au, out_u, y, gw[t - 1] / (float)NN, out_loss);
    node_kernel<<<NB, 256, 0, stream>>>(
        h, hb16, mto, mfr, prb,
        psi_w1 + t * 784, psi_b1 + t * 16, psi_w2 + t * 256, psi_b2 + t * 16,
        dec_w1 + t * 256, dec_b1 + t * 16, dec_w2 + t * 16, dec_b2 + t, out_u);
  }

  // final residual loss (t = 2's u)
  gather_kernel<false, true><<<NB, 256, 0, stream>>>(
      h, hb16, pay, base,
      phi_to_w1, phi_to_b1, phi_to_w2, phi_to_b2,
      phi_fr_w1, phi_fr_b1, phi_fr_w2, phi_fr_b2,
      mto, mfr, 0, pay_au, out_u, y, gw[2] / (float)NN, out_loss);
}